// Round 5
// baseline (4810.219 us; speedup 1.0000x reference)
//
#include <hip/hip_runtime.h>
#include <hip/hip_bf16.h>
#include <math.h>

using bf16 = __hip_bfloat16;

#define DI static __device__ __forceinline__

constexpr int Bc = 8, Nn = 4096, Gc = 128, Kc = 16, Vc = 64, Mc = 64;
constexpr int Dd = 384, NHh = 8, DHh = 48, FFf = 1536;

typedef __bf16 bf8v __attribute__((ext_vector_type(8)));
typedef float f4v __attribute__((ext_vector_type(4)));

DI float b2f(bf16 h) { return __bfloat162float(h); }
DI __bf16 f2b(float f) { return (__bf16)f; }

// async global->LDS, 16B per lane; LDS dest is wave-uniform base (+lane*16 implicit)
DI void gld16(const void* g, void* l) {
    __builtin_amdgcn_global_load_lds((const __attribute__((address_space(1))) void*)g,
                                     (__attribute__((address_space(3))) void*)l, 16, 0, 0);
}

// -------------------- dtype autodetect (inputs) --------------------
__global__ __launch_bounds__(256) void detect_kernel(const unsigned int* __restrict__ w, int* __restrict__ flag) {
    __shared__ int sh[256];
    int cnt = 0;
    for (int i = threadIdx.x; i < 16384; i += 256) {
        unsigned int lo = w[i] & 0xffffu;
        int e = (int)((lo >> 7) & 0xffu);
        if (e < 100 || e > 140) cnt++;
    }
    sh[threadIdx.x] = cnt;
    __syncthreads();
    for (int s = 128; s > 0; s >>= 1) {
        if (threadIdx.x < s) sh[threadIdx.x] += sh[threadIdx.x + s];
        __syncthreads();
    }
    if (threadIdx.x == 0) flag[0] = (sh[0] < 2048) ? 1 : 0;
}

DI float ldf(const void* p, size_t i, int isbf) {
    return isbf ? b2f(((const bf16*)p)[i]) : ((const float*)p)[i];
}

__global__ void cvtf_kernel(const void* __restrict__ src, float* __restrict__ dst, size_t n,
                            const int* __restrict__ flag) {
    size_t t = (size_t)blockIdx.x * 256 + threadIdx.x;
    if (t < n) dst[t] = ldf(src, t, flag[0]);
}

// weight transpose+round: src [cnt][K][N] -> dst [cnt][N][Kpad] bf16, zero-padded K
__global__ void wtr_kernel(const void* __restrict__ src, __bf16* __restrict__ dst,
                           int K, int N, int Kpad, int cnt, const int* __restrict__ flag) {
    size_t t = (size_t)blockIdx.x * 256 + threadIdx.x;
    size_t total = (size_t)cnt * N * Kpad;
    if (t >= total) return;
    int k = (int)(t % Kpad);
    size_t rem = t / Kpad;
    int n = (int)(rem % N);
    int mat = (int)(rem / N);
    float v = (k < K) ? ldf(src, ((size_t)mat * K + k) * N + n, flag[0]) : 0.f;
    dst[t] = f2b(v);
}

__global__ void zero_kernel(unsigned char* __restrict__ p, size_t n) {
    size_t t = (size_t)blockIdx.x * 256 + threadIdx.x;
    if (t < n) p[t] = 0;
}

// -------------------- FPS: centers kept in LDS (no global ops in loop) --------------------
__global__ __launch_bounds__(256) void fps_kernel(const float* __restrict__ pos_a, const float* __restrict__ pos_b,
                                                  float* __restrict__ cent_a, float* __restrict__ cent_b) {
    __shared__ float px[Nn], py[Nn], pz[Nn];
    __shared__ float csx[Gc], csy[Gc], csz[Gc];
    __shared__ float wv[4];
    __shared__ int wi[4];
    __shared__ int chosen;
    int side = blockIdx.x >> 3, b = blockIdx.x & 7, tid = threadIdx.x;
    const float* pos = side ? pos_b : pos_a;
    float* cent = (side ? cent_b : cent_a) + (size_t)b * Gc * 3;
    const float* p = pos + (size_t)b * Nn * 3;
    for (int i = tid; i < Nn; i += 256) { px[i] = p[3*i]; py[i] = p[3*i+1]; pz[i] = p[3*i+2]; }
    __syncthreads();
    float cx = px[0], cy = py[0], cz = pz[0];
    if (tid == 0) { csx[0] = cx; csy[0] = cy; csz[0] = cz; }
    float mind[16];
#pragma unroll
    for (int j = 0; j < 16; j++) {
        int i = tid + 256 * j;
        float dx = px[i]-cx, dy = py[i]-cy, dz = pz[i]-cz;
        mind[j] = __fadd_rn(__fadd_rn(__fmul_rn(dx,dx), __fmul_rn(dy,dy)), __fmul_rn(dz,dz));
    }
    for (int s = 1; s < Gc; s++) {
        float bv = -1.f; int bi = 0;
#pragma unroll
        for (int j = 0; j < 16; j++) { int i = tid + 256*j; if (mind[j] > bv) { bv = mind[j]; bi = i; } }
        for (int o = 32; o > 0; o >>= 1) {
            float v2 = __shfl_down(bv, o, 64); int i2 = __shfl_down(bi, o, 64);
            if (v2 > bv || (v2 == bv && i2 < bi)) { bv = v2; bi = i2; }
        }
        if ((tid & 63) == 0) { wv[tid >> 6] = bv; wi[tid >> 6] = bi; }
        __syncthreads();
        if (tid == 0) {
            float fv = wv[0]; int fi = wi[0];
            for (int k = 1; k < 4; k++)
                if (wv[k] > fv || (wv[k] == fv && wi[k] < fi)) { fv = wv[k]; fi = wi[k]; }
            chosen = fi;
            csx[s] = px[fi]; csy[s] = py[fi]; csz[s] = pz[fi];
        }
        __syncthreads();
        int ci = chosen;
        float qx = px[ci], qy = py[ci], qz = pz[ci];
#pragma unroll
        for (int j = 0; j < 16; j++) {
            int i = tid + 256 * j;
            float dx = px[i]-qx, dy = py[i]-qy, dz = pz[i]-qz;
            float d = __fadd_rn(__fadd_rn(__fmul_rn(dx,dx), __fmul_rn(dy,dy)), __fmul_rn(dz,dz));
            if (d < mind[j]) mind[j] = d;
        }
    }
    __syncthreads();
    for (int i = tid; i < Gc; i += 256) {
        cent[3*i] = csx[i]; cent[3*i+1] = csy[i]; cent[3*i+2] = csz[i];
    }
}

// -------------------- brute-force KNN (k=16), tie -> lower index --------------------
__global__ __launch_bounds__(64) void knn16_kernel(const float* __restrict__ q, const float* __restrict__ r,
                                                   int* __restrict__ nidx, int NQ, int NR) {
    __shared__ float dist[4096];
    int blk = blockIdx.x; int b = blk / NQ, qi = blk % NQ;
    int lane = threadIdx.x;
    const float* qp = q + ((size_t)b * NQ + qi) * 3;
    float qx = qp[0], qy = qp[1], qz = qp[2];
    float qq = __fadd_rn(__fadd_rn(__fmul_rn(qx,qx), __fmul_rn(qy,qy)), __fmul_rn(qz,qz));
    const float* rp = r + (size_t)b * NR * 3;
    for (int i = lane; i < NR; i += 64) {
        float rx = rp[3*i], ry = rp[3*i+1], rz = rp[3*i+2];
        float rr = __fadd_rn(__fadd_rn(__fmul_rn(rx,rx), __fmul_rn(ry,ry)), __fmul_rn(rz,rz));
        float dot = __fadd_rn(__fadd_rn(__fmul_rn(qx,rx), __fmul_rn(qy,ry)), __fmul_rn(qz,rz));
        dist[i] = __fadd_rn(__fadd_rn(qq, rr), -2.f * dot);
    }
    __syncthreads();
    int* out = nidx + ((size_t)b * NQ + qi) * Kc;
    for (int sel = 0; sel < Kc; ++sel) {
        float bv = INFINITY; int bi = 0;
        bool has = false;
        for (int i = lane; i < NR; i += 64) {
            float v = dist[i];
            if (!has || v < bv) { bv = v; bi = i; has = true; }
        }
        for (int o = 32; o > 0; o >>= 1) {
            float v2 = __shfl_xor(bv, o, 64); int i2 = __shfl_xor(bi, o, 64);
            if (v2 < bv || (v2 == bv && i2 < bi)) { bv = v2; bi = i2; }
        }
        if (lane == 0) { out[sel] = bi; dist[bi] = INFINITY; }
        __syncthreads();
    }
}

// -------------------- top-3 centers + interp weights --------------------
__global__ __launch_bounds__(64) void knn3_kernel(const float* __restrict__ pos, const float* __restrict__ cent,
                                                  int* __restrict__ idx3, float* __restrict__ w3) {
    int bn = blockIdx.x; int b = bn / Nn;
    int lane = threadIdx.x;
    const float* p = pos + (size_t)bn * 3;
    float px = p[0], py = p[1], pz = p[2];
    float pp = __fadd_rn(__fadd_rn(__fmul_rn(px,px), __fmul_rn(py,py)), __fmul_rn(pz,pz));
    float dv[2]; int di[2];
#pragma unroll
    for (int c = 0; c < 2; c++) {
        int g = lane + 64 * c;
        const float* cp = cent + ((size_t)b * Gc + g) * 3;
        float cx = cp[0], cy = cp[1], cz = cp[2];
        float cc = __fadd_rn(__fadd_rn(__fmul_rn(cx,cx), __fmul_rn(cy,cy)), __fmul_rn(cz,cz));
        float dot = __fadd_rn(__fadd_rn(__fmul_rn(px,cx), __fmul_rn(py,cy)), __fmul_rn(pz,cz));
        dv[c] = __fadd_rn(__fadd_rn(pp, cc), -2.f * dot);
        di[c] = g;
    }
    float od[3]; int oi[3];
#pragma unroll
    for (int r = 0; r < 3; r++) {
        float bv; int bi;
        if (dv[1] < dv[0]) { bv = dv[1]; bi = di[1]; } else { bv = dv[0]; bi = di[0]; }
        for (int o = 32; o > 0; o >>= 1) {
            float v2 = __shfl_xor(bv, o, 64); int i2 = __shfl_xor(bi, o, 64);
            if (v2 < bv || (v2 == bv && i2 < bi)) { bv = v2; bi = i2; }
        }
        od[r] = bv; oi[r] = bi;
        if (di[0] == bi) dv[0] = INFINITY;
        if (di[1] == bi) dv[1] = INFINITY;
    }
    if (lane == 0) {
        float w[3], s = 0.f;
        for (int r = 0; r < 3; r++) { w[r] = 1.f / (fmaxf(od[r], 0.f) + 1e-8f); s += w[r]; }
        for (int r = 0; r < 3; r++) { idx3[(size_t)bn*3 + r] = oi[r]; w3[(size_t)bn*3 + r] = w[r] / s; }
    }
}

// interp for rows [r0, r0+CH): out local (CH,448) bf16, cols 387..447 zero
__global__ void interp_kernel(const float* __restrict__ feats, const float* __restrict__ pos,
                              const int* __restrict__ idx3, const float* __restrict__ w3,
                              __bf16* __restrict__ x448, int r0, int CH) {
    size_t t = (size_t)blockIdx.x * 256 + threadIdx.x;
    size_t total = (size_t)CH * 448;
    if (t >= total) return;
    int c = (int)(t % 448); size_t i = t / 448;
    size_t r = (size_t)r0 + i; int b = (int)(r / Nn);
    float o = 0.f;
    if (c < Dd) {
        for (int k = 0; k < 3; k++)
            o += w3[r*3 + k] * feats[((size_t)b * Gc + idx3[r*3 + k]) * Dd + c];
    } else if (c < 387) {
        o = pos[r*3 + (c - Dd)];
    }
    x448[t] = f2b(o);
}

// -------------------- tokenize helpers --------------------
__global__ void rel_kernel(const float* __restrict__ pos, const float* __restrict__ cent,
                           const int* __restrict__ nidx, __bf16* __restrict__ rel, int nb) {
    int t = blockIdx.x * 256 + threadIdx.x;
    if (t >= nb * Gc * Kc * 64) return;
    int c = t & 63; int row = t >> 6;
    float v = 0.f;
    if (c < 3) {
        int g = (row / Kc) % Gc; int b = row / (Kc * Gc);
        int pi = nidx[row];
        v = pos[((size_t)b * Nn + pi) * 3 + c] - cent[((size_t)b * Gc + g) * 3 + c];
    }
    rel[t] = f2b(v);
}

__global__ void maxk_f32_kernel(const float* __restrict__ in, float* __restrict__ out, int BG, int C) {
    int t = blockIdx.x * 256 + threadIdx.x;
    if (t >= BG * C) return;
    int c = t % C; int bg = t / C;
    const float* p = in + (size_t)bg * Kc * C + c;
    float m = -INFINITY;
    for (int k = 0; k < Kc; k++) m = fmaxf(m, p[(size_t)k * C]);
    out[t] = m;
}

__global__ void maxk_bf_kernel(const __bf16* __restrict__ in, __bf16* __restrict__ out, int BG, int C) {
    int t = blockIdx.x * 256 + threadIdx.x;
    if (t >= BG * C) return;
    int c = t % C; int bg = t / C;
    const __bf16* p = in + (size_t)bg * Kc * C + c;
    float m = -INFINITY;
    for (int k = 0; k < Kc; k++) m = fmaxf(m, (float)p[(size_t)k * C]);
    out[t] = f2b(m);
}

__global__ void concat_gf_kernel(const __bf16* __restrict__ g, const __bf16* __restrict__ f,
                                 __bf16* __restrict__ cat, int BG) {
    size_t t = (size_t)blockIdx.x * 256 + threadIdx.x;
    size_t total = (size_t)BG * Kc * 512;
    if (t >= total) return;
    int c = (int)(t % 512); size_t bgk = t / 512; size_t bg = bgk / Kc;
    cat[t] = (c < 256) ? g[bg * 256 + c] : f[bgk * 256 + (c - 256)];
}

// -------------------- gather / masks --------------------
__global__ void gather_rows_kernel(const float* __restrict__ in, const int* __restrict__ idx,
                                   float* __restrict__ out, int Ni, int C, int Sin) {
    size_t t = (size_t)blockIdx.x * 256 + threadIdx.x;
    size_t total = (size_t)Bc * Ni * C;
    if (t >= total) return;
    int c = (int)(t % C); size_t bi = t / C; int i = (int)(bi % Ni); int b = (int)(bi / Ni);
    int r = idx[(size_t)b * Ni + i];
    out[t] = in[((size_t)b * Sin + r) * C + c];
}

__global__ void scatter_mask_kernel(const int* __restrict__ nidx, unsigned char* __restrict__ mask,
                                    int Q, int S, int nb) {
    int t = blockIdx.x * 256 + threadIdx.x;
    if (t >= nb * Q * Kc) return;
    int q = (t / Kc) % Q; int b = t / (Kc * Q);
    mask[((size_t)b * Q + q) * S + nidx[t]] = 1;
}

// -------------------- positional encoding (standalone, for cpe) --------------------
__global__ void pe_kernel(float* __restrict__ dst, const float* __restrict__ base,
                          const float* __restrict__ xyz, size_t total) {
    size_t t = (size_t)blockIdx.x * 256 + threadIdx.x;
    if (t >= total) return;
    int d = (int)(t % Dd); size_t bs = t / Dd;
    int c = d >> 7;
    int i = d & 127;
    int j = i >> 1;
    float inv = __expf(-0.1439115683121279f * (float)j);  // 10000^(-j/64)
    float val = xyz[bs * 3 + c] * inv;
    float pe = (i & 1) ? __cosf(val) : __sinf(val);
    dst[t] = (base ? base[t] : 0.f) + pe;
}

// -------------------- fused add + LayerNorm, row=384, bf16 out --------------------
__global__ __launch_bounds__(256) void ln2_kernel(const float* __restrict__ A, const float* __restrict__ B,
                                                  __bf16* __restrict__ Y, int R) {
    int lane = threadIdx.x & 63;
    int row = blockIdx.x * 4 + (threadIdx.x >> 6);
    if (row >= R) return;
    const float* a = A + (size_t)row * Dd;
    const float* b = B + (size_t)row * Dd;
    float v[6]; float s = 0.f;
#pragma unroll
    for (int j = 0; j < 6; j++) { v[j] = a[lane + 64*j] + b[lane + 64*j]; s += v[j]; }
#pragma unroll
    for (int o = 32; o > 0; o >>= 1) s += __shfl_xor(s, o, 64);
    float m = s * (1.f / Dd);
    float s2 = 0.f;
#pragma unroll
    for (int j = 0; j < 6; j++) { float d = v[j] - m; s2 += d * d; }
#pragma unroll
    for (int o = 32; o > 0; o >>= 1) s2 += __shfl_xor(s2, o, 64);
    float inv = rsqrtf(s2 * (1.f / Dd) + 1e-5f);
    __bf16* y = Y + (size_t)row * Dd;
#pragma unroll
    for (int j = 0; j < 6; j++) y[lane + 64*j] = f2b((v[j] - m) * inv);
}

// -------------------- MFMA bf16 GEMM, 128x128 tile, global_load_lds + XOR swizzle --------------------
// LDS[row][slot s] = A[row][k0 + 8*(s ^ (row&7))]; fragment reads XOR byte-col with (m&7)<<4.
// Optional pe epilogue (pepos non-null, obf=0): v += sin/cos(pos[gm]*10000^-j) per pe_kernel formula.
__global__ __launch_bounds__(256) void gemm_kernel(const __bf16* __restrict__ A, const __bf16* __restrict__ Wt,
                                                   const float* __restrict__ bias,
                                                   const float* __restrict__ res, void* __restrict__ Cv,
                                                   int M, int Ncols, int Kk, int relu, int obf,
                                                   const float* __restrict__ pepos) {
    __shared__ alignas(16) __bf16 As[128*64];
    __shared__ alignas(16) __bf16 Bs[128*64];
    const int tid = threadIdx.x;
    const int row0 = blockIdx.y * 128, col0 = blockIdx.x * 128;
    const int w = tid >> 6, lane = tid & 63, m = lane & 15, q = lane >> 4;
    const int wr = w >> 1, wc = w & 1;
    const int l8 = lane >> 3, l7 = lane & 7;
    const __bf16* apg = A  + (size_t)(row0 + 32*w + l8) * Kk + 8*(l7 ^ l8);
    const __bf16* wpg = Wt + (size_t)(col0 + 32*w + l8) * Kk + 8*(l7 ^ l8);
    const int swz = (m & 7) << 4;
    const char* asb = (const char*)As;
    const char* bsb = (const char*)Bs;

    f4v acc[4][4];
#pragma unroll
    for (int r = 0; r < 4; r++)
#pragma unroll
        for (int n = 0; n < 4; n++) acc[r][n] = (f4v){0.f, 0.f, 0.f, 0.f};

    for (int k0 = 0; k0 < Kk; k0 += 64) {
#pragma unroll
        for (int i = 0; i < 4; i++) {
            gld16(apg + k0 + (size_t)(8*i) * Kk, As + w*2048 + i*512);
            gld16(wpg + k0 + (size_t)(8*i) * Kk, Bs + w*2048 + i*512);
        }
        __syncthreads();
#pragma unroll
        for (int kk = 0; kk < 2; kk++) {
            bf8v bfr[4], afr[4];
#pragma unroll
            for (int n = 0; n < 4; n++)
                bfr[n] = *(const bf8v*)(bsb + (wc*64 + n*16 + m)*128 + ((kk*64 + q*16) ^ swz));
#pragma unroll
            for (int r = 0; r < 4; r++)
                afr[r] = *(const bf8v*)(asb + (wr*64 + r*16 + m)*128 + ((kk*64 + q*16) ^ swz));
#pragma unroll
            for (int r = 0; r < 4; r++)
#pragma unroll
                for (int n = 0; n < 4; n++)
                    acc[r][n] = __builtin_amdgcn_mfma_f32_16x16x32_bf16(afr[r], bfr[n], acc[r][n], 0, 0, 0);
        }
        __syncthreads();
    }
#pragma unroll
    for (int n = 0; n < 4; n++) {
        const int gn = col0 + wc*64 + n*16 + m;
        float bv = bias ? bias[gn] : 0.f;
        const int pi = gn & 127, pc = gn >> 7, pj = pi >> 1;
        const float pinv = pepos ? __expf(-0.1439115683121279f * (float)pj) : 0.f;
#pragma unroll
        for (int r = 0; r < 4; r++) {
#pragma unroll
            for (int j = 0; j < 4; j++) {
                int gm = row0 + wr*64 + r*16 + q*4 + j;
                float v = acc[r][n][j] + bv;
                if (relu) v = fmaxf(v, 0.f);
                if (pepos) {
                    float val = pepos[(size_t)gm*3 + pc] * pinv;
                    v += (pi & 1) ? __cosf(val) : __sinf(val);
                }
                if (res) v += res[(size_t)gm * Ncols + gn];
                if (obf) ((__bf16*)Cv)[(size_t)gm * Ncols + gn] = f2b(v);
                else     ((float*)Cv)[(size_t)gm * Ncols + gn] = v;
            }
        }
    }
}

// -------------------- MFMA GEMM with fused LayerNorm on A (f32 in, K=384) --------------------
// Stats phase replicates ln_kernel's exact reduction order (bit-identical), then reg-staged
// LN-applied A staging into the same swizzled LDS layout; B via global_load_lds.
__global__ __launch_bounds__(256) void gemmln_kernel(const float* __restrict__ Af, const __bf16* __restrict__ Wt,
                                                     const float* __restrict__ bias,
                                                     const float* __restrict__ res, void* __restrict__ Cv,
                                                     int M, int Ncols, int Kk, int relu, int obf) {
    __shared__ alignas(16) __bf16 As[128*64];
    __shared__ alignas(16) __bf16 Bs[128*64];
    __shared__ float mu[128], iv[128];
    const int tid = threadIdx.x;
    const int row0 = blockIdx.y * 128, col0 = blockIdx.x * 128;
    const int w = tid >> 6, lane = tid & 63, m = lane & 15, q = lane >> 4;
    const int wr = w >> 1, wc = w & 1;
    const int l8 = lane >> 3, l7 = lane & 7;
    const __bf16* wpg = Wt + (size_t)(col0 + 32*w + l8) * Kk + 8*(l7 ^ l8);
    const int swz = (m & 7) << 4;
    const char* asb = (const char*)As;
    const char* bsb = (const char*)Bs;

    // per-row LN stats; wave w handles rows w*32..w*32+31
    for (int r = 0; r < 32; r++) {
        int row = w*32 + r;
        const float* x = Af + (size_t)(row0 + row) * Kk;
        float v[6]; float s = 0.f;
#pragma unroll
        for (int j = 0; j < 6; j++) { v[j] = x[lane + 64*j]; s += v[j]; }
#pragma unroll
        for (int o = 32; o > 0; o >>= 1) s += __shfl_xor(s, o, 64);
        float mean = s * (1.f / Dd);
        float s2 = 0.f;
#pragma unroll
        for (int j = 0; j < 6; j++) { float d = v[j] - mean; s2 += d * d; }
#pragma unroll
        for (int o = 32; o > 0; o >>= 1) s2 += __shfl_xor(s2, o, 64);
        if (lane == 0) { mu[row] = mean; iv[row] = rsqrtf(s2 * (1.f / Dd) + 1e-5f); }
    }
    __syncthreads();
    const int srow = tid >> 1, s0 = (tid & 1) * 4;
    const float* arow = Af + (size_t)(row0 + srow) * Kk;
    const float mean_ = mu[srow], inv_ = iv[srow];

    f4v acc[4][4];
#pragma unroll
    for (int r = 0; r < 4; r++)
#pragma unroll
        for (int n = 0; n < 4; n++) acc[r][n] = (f4v){0.f, 0.f, 0.f, 0.f};

    for (int k0 = 0; k0 < Kk; k0 += 64) {
#pragma unroll
        for (int i = 0; i < 4; i++)
            gld16(wpg + k0 + (size_t)(8*i) * Kk, Bs + w*2048 + i*512);
        // stage A with LN applied; slot order rotated by row to spread banks
#pragma unroll
        for (int si = 0; si < 4; si++) {
            int s = s0 + ((si + srow) & 3);
            int srck = k0 + 8*(s ^ (srow & 7));
            float4 f0 = *reinterpret_cast<const float4*>(arow + srck);
            float4 f1 = *reinterpret_cast<const float4*>(arow + srck + 4);
            union { __bf16 h[8]; uint4 u; } t;
            t.h[0] = f2b((f0.x - mean_) * inv_); t.h[1] = f2b((f0.y - mean_) * inv_);
            t.h[2] = f2b((f0.z - mean_) * inv_); t.h[3] = f2b((f0.w - mean_) * inv_);
            t.h[4] = f2b((f1.x - mean_) * inv_); t.h[5] = f2b((f1.y - mean_) * inv_);
            t.h[6] = f2b((f1.z - mean_) * inv_); t.h[7] = f2b((f1.w - mean_) * inv_);
            *reinterpret_cast<uint4*>(&As[srow*64 + s*8]) = t.u;
        }
        __syncthreads();
#pragma unroll
        for (int kk = 0; kk < 2; kk++) {
            bf8v bfr[4], afr[4];
#pragma unroll
            for (int n = 0; n < 4; n++)
                bfr[n] = *(const bf8v*)(bsb + (wc*64 + n*16 + m)*128 + ((kk*64 + q*16) ^ swz));
#pragma unroll
            for (int r = 0; r < 4; r++)
                afr[r] = *(const bf8v*)(asb + (wr*64 + r*16 + m)*128 + ((kk*64 + q*16) ^ swz));
#pragma unroll
            for (int r = 0; r < 4; r++)
#pragma unroll
                for (int n = 0; n < 4; n++)
                    acc[r][n] = __builtin_amdgcn_mfma_f32_16x16x32_bf16(afr[r], bfr[n], acc[r][n], 0, 0, 0);
        }
        __syncthreads();
    }
#pragma unroll
    for (int n = 0; n < 4; n++) {
        const int gn = col0 + wc*64 + n*16 + m;
        float bv = bias ? bias[gn] : 0.f;
#pragma unroll
        for (int r = 0; r < 4; r++) {
#pragma unroll
            for (int j = 0; j < 4; j++) {
                int gm = row0 + wr*64 + r*16 + q*4 + j;
                float v = acc[r][n][j] + bv;
                if (relu) v = fmaxf(v, 0.f);
                if (res) v += res[(size_t)gm * Ncols + gn];
                if (obf) ((__bf16*)Cv)[(size_t)gm * Ncols + gn] = f2b(v);
                else     ((float*)Cv)[(size_t)gm * Ncols + gn] = v;
            }
        }
    }
}

// -------------------- MFMA attention: Sk=128, DH=48, optional mask + kv-batch xor --------------------
__global__ __launch_bounds__(256) void attn_mfma_kernel(const __bf16* __restrict__ Qb,
                                                        const __bf16* __restrict__ Kp,
                                                        const __bf16* __restrict__ Vp,
                                                        __bf16* __restrict__ O,
                                                        int ldq, int ldkv, int ldo, int rpb, int b0,
                                                        int bxor, const unsigned char* __restrict__ Mk) {
    __shared__ alignas(16) char smem[128*136*2 + 48*136*2];
    __bf16 (*Ks)[72]  = (__bf16(*)[72])smem;
    __bf16 (*Pl)[136] = (__bf16(*)[136])smem;            // aliases Ks after QK
    __bf16 (*Vt)[136] = (__bf16(*)[136])(smem + 128*136*2);
    const int tid = threadIdx.x;
    const int h = blockIdx.y, z = blockIdx.z;
    const int bk = (b0 + z) ^ bxor;
    const size_t row0 = (size_t)z * rpb + (size_t)blockIdx.x * 128;
    {
        int r = tid >> 1, c0 = (tid & 1) * 24;
        const __bf16* kp = Kp + ((size_t)bk * 128 + r) * ldkv + h * 48 + c0;
        *reinterpret_cast<bf8v*>(&Ks[r][c0])      = *reinterpret_cast<const bf8v*>(kp);
        *reinterpret_cast<bf8v*>(&Ks[r][c0 + 8])  = *reinterpret_cast<const bf8v*>(kp + 8);
        *reinterpret_cast<bf8v*>(&Ks[r][c0 + 16]) = *reinterpret_cast<const bf8v*>(kp + 16);
        if (tid & 1) {
            *reinterpret_cast<bf8v*>(&Ks[r][48]) = (bf8v){};
            *reinterpret_cast<bf8v*>(&Ks[r][56]) = (bf8v){};
        }
        const __bf16* vp = Vp + ((size_t)bk * 128 + r) * ldkv + h * 48 + c0;
        bf8v w0 = *reinterpret_cast<const bf8v*>(vp);
        bf8v w1 = *reinterpret_cast<const bf8v*>(vp + 8);
        bf8v w2 = *reinterpret_cast<const bf8v*>(vp + 16);
#pragma unroll
        for (int i = 0; i < 8; i++) {
            Vt[c0 + i][r] = w0[i]; Vt[c0 + 8 + i][r] = w1[i]; Vt[c0 + 16 + i][r] = w2[i];
        }
    }
    __syncthreads();
    const int w = tid >> 6, lane = tid & 63, m = lane & 15, q = lane >> 4;
    const __bf16* qbase = Qb + (row0 + (size_t)(w*32 + m)) * ldq + h * 48;
    f4v sc[2][8];
#pragma unroll
    for (int rt = 0; rt < 2; rt++)
#pragma unroll
        for (int nt = 0; nt < 8; nt++) sc[rt][nt] = (f4v){0.f, 0.f, 0.f, 0.f};
#pragma unroll
    for (int kk = 0; kk < 2; kk++) {
        bf8v a0 = *reinterpret_cast<const bf8v*>(qbase + kk*32 + q*8);
        bf8v a1 = *reinterpret_cast<const bf8v*>(qbase + (size_t)16*ldq + kk*32 + q*8);
#pragma unroll
        for (int nt = 0; nt < 8; nt++) {
            bf8v bf = *reinterpret_cast<bf8v*>(&Ks[nt*16 + m][kk*32 + q*8]);
            sc[0][nt] = __builtin_amdgcn_mfma_f32_16x16x32_bf16(a0, bf, sc[0][nt], 0, 0, 0);
            sc[1][nt] = __builtin_amdgcn_mfma_f32_16x16x32_bf16(a1, bf, sc[1][nt], 0, 0, 0);
        }
    }
    const float scale = 0.14433756729740643f;  // 1/sqrt(48)
    float inv_[2][4];
#pragma unroll
    for (int rt = 0; rt < 2; rt++) {
#pragma unroll
        for (int j = 0; j < 4; j++) {
            const unsigned char* mr = Mk ?
                (Mk + ((size_t)z * rpb + (size_t)blockIdx.x*128 + (w*32 + rt*16 + q*4 + j)) * 128 + m) : nullptr;
            float mv = -INFINITY;
#pragma unroll
            for (int nt = 0; nt < 8; nt++) {
                float vs = sc[rt][nt][j] * scale;
                if (mr && !mr[nt*16]) vs = -1e9f;
                sc[rt][nt][j] = vs;
                mv = fmaxf(mv, vs);
            }
#pragma unroll
            for (int o = 8; o > 0; o >>= 1) mv = fmaxf(mv, __shfl_xor(mv, o, 64));
            float sum = 0.f;
#pragma unroll
            for (int nt = 0; nt < 8; nt++) {
                float e = __expf(sc[rt][nt][j] - mv);
                sc[rt][nt][j] = e; sum += e;
            }
#pragma unroll
            for (int o = 8; o > 0; o >>= 1) sum += __shfl_xor(sum, o, 64);
            inv_[rt][j] = 1.f / sum;
        }
    }
    __syncthreads();
#pragma unroll
    for (int rt = 0; rt < 2; rt++)
#pragma unroll
        for (int nt = 0; nt < 8; nt++)
#pragma unroll
            for (int j = 0; j < 4; j++)
                Pl[w*32 + rt*16 + q*4 + j][nt*16 + m] = f2b(sc[rt][nt][j]);
    __syncthreads();
    f4v ov[2][3];
#pragma unroll
    for (int rt = 0; rt < 2; rt++)
#pragma unroll
        for (int nt = 0; nt < 3; nt++) ov[rt][nt] = (f4v){0.f, 0.f, 0.f, 0.f};
#pragma unroll
    for (int kk = 0; kk < 4; kk++) {
        bf8v p0 = *reinterpret_cast<bf8v*>(&Pl[w*32 + m][kk*32 + q*8]);
        bf8v p1 = *reinterpret_cast<bf8v*>(&Pl[w*32 + 16 + m][kk*32 + q*8]);
#pragma unroll
        for (int nt = 0; nt < 3; nt++) {
            bf8v bv = *reinterpret_cast<bf8v*>(&Vt[nt*16 + m][kk*32 + q*8]);
            ov[0][nt] = __builtin_amdgcn_mfma_f32_16x16x32_bf16(p0, bv, ov[0][nt], 0, 0, 0);
            ov[1][nt] = __builtin_amdgcn_mfma_f32_16x16x32_bf16(p1, bv, ov[1][nt], 0, 0, 0);
        }
    }
    __bf16* op = O + (row0 + (size_t)(w*32)) * ldo + h * 48;
#pragma unroll
    for (int rt = 0; rt < 2; rt++)
#pragma unroll
        for (int nt = 0; nt < 3; nt++)
#pragma unroll
            for (int j = 0; j < 4; j++)
                op[(size_t)(rt*16 + q*4 + j) * ldo + nt*16 + m] = f2b(ov[rt][nt][j] * inv_[rt][j]);
}

// -------------------- scalar attention (S=64 vis path), xor batch pairing --------------------
__global__ __launch_bounds__(64) void attn_kernel(const float* __restrict__ Q, const float* __restrict__ Kb,
                                                  const float* __restrict__ Vb,
                                                  const unsigned char* __restrict__ mask,
                                                  __bf16* __restrict__ O, int Sq, int Sk, int xorv,
                                                  int ldq, int ldkv) {
    int qi = blockIdx.x, h = blockIdx.y, bq = blockIdx.z;
    int bk = bq ^ xorv;
    int lane = threadIdx.x;
    __shared__ float qv[DHh];
    __shared__ float pv[128];
    const size_t qrow = (size_t)bq * Sq + qi;
    if (lane < DHh) qv[lane] = Q[qrow * ldq + h * DHh + lane];
    __syncthreads();
    const float scale = 0.14433756729740643f;  // 1/sqrt(48)
    float lv[2] = {-INFINITY, -INFINITY};
#pragma unroll
    for (int c = 0; c < 2; c++) {
        int s = lane + 64 * c;
        if (s < Sk) {
            const float* kr = Kb + ((size_t)bk * Sk + s) * ldkv + h * DHh;
            float d = 0.f;
#pragma unroll
            for (int t = 0; t < DHh; t++) d += qv[t] * kr[t];
            d *= scale;
            if (mask && !mask[qrow * Sk + s]) d = -1e9f;
            lv[c] = d;
        }
    }
    float mx = fmaxf(lv[0], lv[1]);
    for (int o = 32; o > 0; o >>= 1) mx = fmaxf(mx, __shfl_xor(mx, o, 64));
    float sum = 0.f;
#pragma unroll
    for (int c = 0; c < 2; c++) {
        int s = lane + 64 * c;
        if (s < Sk) { float e = expf(lv[c] - mx); pv[s] = e; sum += e; }
    }
    for (int o = 32; o > 0; o >>= 1) sum += __shfl_xor(sum, o, 64);
    float inv = 1.f / sum;
    __syncthreads();
    if (lane < DHh) {
        float acc = 0.f;
        const float* vb = Vb + ((size_t)bk * Sk) * ldkv + h * DHh + lane;
        for (int s = 0; s < Sk; s++) acc += pv[s] * vb[(size_t)s * ldkv];
        O[qrow * Dd + h * DHh + lane] = f2b(acc * inv);
    }
}

// -------------------- decoder q init --------------------
__global__ void dec_init_kernel(const float* __restrict__ mtok, const float* __restrict__ vout,
                                const float* __restrict__ cpe, const int* __restrict__ mski,
                                const int* __restrict__ visi, float* __restrict__ x) {
    size_t t = (size_t)blockIdx.x * 256 + threadIdx.x;
    size_t total = (size_t)Bc * Gc * Dd;
    if (t >= total) return;
    int d = (int)(t % Dd); size_t bi = t / Dd; int i = (int)(bi % Gc); int b = (int)(bi / Gc);
    float base; int ci;
    if (i < Mc) { base = mtok[d]; ci = mski[b * Mc + i]; }
    else        { base = vout[((size_t)b * Vc + (i - Mc)) * Dd + d]; ci = visi[b * Vc + (i - Mc)]; }
    x[t] = base + cpe[((size_t)b * Gc + ci) * Dd + d];
}

// -------------------- smooth-L1 partial reduce --------------------
__global__ __launch_bounds__(256) void sl1_kernel(const float* __restrict__ tgt, const float* __restrict__ dec,
                                                  float* __restrict__ acc, int slot) {
    __shared__ float sh[256];
    size_t t = (size_t)blockIdx.x * 256 + threadIdx.x;
    const size_t total = (size_t)Bc * Mc * Dd;
    float v = 0.f;
    if (t < total) {
        int d = (int)(t % Dd); size_t rem = t / Dd; int i = (int)(rem % Mc); int b = (int)(rem / Mc);
        float p = dec[((size_t)b * Gc + i) * Dd + d];
        float a = fabsf(p - tgt[t]);
        v = (a < 2.f) ? 0.25f * a * a : (a - 1.f);
    }
    sh[threadIdx.x] = v;
    __syncthreads();
    for (int s = 128; s > 0; s >>= 1) {
        if (threadIdx.x < s) sh[threadIdx.x] += sh[threadIdx.x + s];
        __syncthreads();
    }
    if (threadIdx.x == 0) atomicAdd(&acc[slot], sh[0]);
}

__global__ void mae_finalize_kernel(const float* __restrict__ acc, float* __restrict__ out) {
    const float inv = 1.f / (float)(Bc * Mc * Dd);
    *out = 0.5f * (acc[0] * inv) + 0.5f * (acc[1] * inv);
}

// ==================== host orchestration ====================
extern "C" void kernel_launch(void* const* d_in, const int* in_sizes, int n_in,
                              void* d_out, int out_size, void* d_ws, size_t ws_size,
                              hipStream_t stream) {
    (void)in_sizes; (void)n_in; (void)out_size;
    const void* pos_src = d_in[0];
    const void* pos_tgt = d_in[1];
    const int* vis_s = (const int*)d_in[2];
    const int* msk_s = (const int*)d_in[3];
    const int* vis_t = (const int*)d_in[4];
    const int* msk_t = (const int*)d_in[5];
    const void *tw1 = d_in[6], *tb1 = d_in[7], *tw2 = d_in[8], *tb2 = d_in[9];
    const void *tw3 = d_in[10], *tb3 = d_in[11], *tw4 = d_in[12], *tb4 = d_in[13];
    const void *mtok = d_in[14];
    const void *cxw = d_in[15], *cff1 = d_in[16], *cff2 = d_in[17];
    const void *esa = d_in[18], *eca = d_in[19], *eff1 = d_in[20], *eff2 = d_in[21];
    const void *dca = d_in[22], *dff1 = d_in[23], *dff2 = d_in[24];
    const void *uw1 = d_in[25], *ub1 = d_in[26], *uw2 = d_in[27], *ub2 = d_in[28];
    float* out = (float*)d_out;
    char* ws = (char*)d_ws;

    const size_t DD = (size_t)Dd * Dd;
    const size_t DF = (size_t)Dd * FFf;
    const size_t GD = (size_t)Gc * Dd;        // 49152
    const size_t PH = (size_t)Bc * Nn * 3;    // posf half (elements)

    // ---- bf16 transposed weight arena (element offsets) ----
    size_t wo = 0;
    auto walloc = [&](size_t e) -> size_t { size_t r = wo; wo += e; return r; };
    const size_t wt_t1 = walloc((size_t)128 * 64);
    const size_t wt_t2 = walloc((size_t)256 * 128);
    const size_t wt_t3 = walloc((size_t)512 * 512);
    const size_t wt_t4 = walloc((size_t)384 * 512);
    const size_t wt_cx = walloc((size_t)8 * DD);
    const size_t wt_cf1 = walloc(DF);
    const size_t wt_cf2 = walloc(DF);
    const size_t wt_es = walloc((size_t)16 * DD);
    const size_t wt_ec = walloc((size_t)16 * DD);
    const size_t wt_ef1 = walloc((size_t)4 * DF);
    const size_t wt_ef2 = walloc((size_t)4 * DF);
    const size_t wt_dc = walloc((size_t)8 * DD);
    const size_t wt_df1 = walloc((size_t)2 * DF);
    const size_t wt_df2 = walloc((size_t)2 * DF);
    const size_t wt_u1 = walloc((size_t)384 * 448);
    const size_t wt_u2 = walloc((size_t)384 * 384);

    // ---- persistent workspace (batches 0..7 = src, 8..15 = tgt) ----
    size_t o = 0;
    auto alloc = [&](size_t bytes) -> size_t { size_t r = o; o += (bytes + 255) & ~(size_t)255; return r; };
    const size_t flagO = alloc(256);
    const size_t wtO = alloc(wo * 2);
    const size_t bsO = alloc(2048 * 4);
    const size_t mtokO = alloc(Dd * 4);
    const size_t posfO = alloc(2 * PH * 4);
    const size_t centO = alloc((size_t)16 * Gc * 3 * 4);
    const size_t cpeO  = alloc((size_t)16 * GD * 4);
    const size_t tokO  = alloc((size_t)16 * GD * 4);
    const size_t vtokO = alloc((size_t)16 * Vc * Dd * 4);
    const size_t lnmO = alloc((size_t)16 * GD * 2);
    const size_t qbO  = alloc((size_t)16 * GD * 2);
    const size_t qkvbO = alloc((size_t)16 * Gc * 1152 * 4);
    const size_t kvbO  = alloc((size_t)16 * Gc * 768 * 2);
    const size_t kvd0O = alloc((size_t)16 * Gc * 768 * 2);
    const size_t kvd1O = alloc((size_t)16 * Gc * 768 * 2);
    const size_t cxO   = alloc((size_t)16 * GD * 2);
    const size_t decxO = alloc((size_t)16 * GD * 4);
    const size_t relbO = alloc((size_t)16 * Gc * Kc * 64 * 2);
    const size_t tbsO = alloc((size_t)Bc * Mc * Dd * 4), tbtO = alloc((size_t)Bc * Mc * Dd * 4);
    const size_t mfullO = alloc((size_t)16 * Gc * Gc);
    const size_t mvisO  = alloc((size_t)16 * Vc * Vc);
    const size_t nidxO = alloc((size_t)16 * Gc * Kc * 4);
    const size_t idx3O = alloc((size_t)16 * Nn * 3 * 4), w3O = alloc((size_t)16 * Nn * 3 * 4);
    const size_t vis3O = alloc((size_t)16 * Vc * 3 * 4);
    const size_t accbO = alloc(64);

    // ---- scratch arena ----
    const size_t arenaO = o;
    const size_t arena_bytes = (ws_size > arenaO) ? (ws_size - arenaO) : 0;
    // dense rows/pass: Acb 896 + Xc 1536 + Lc 768 + QT 768 + T2 768 + Hh 3072 = 7808 B/row
    int RP = 128;
    {
        const int cands[10] = {65536, 32768, 16384, 8192, 4096, 2048, 1024, 512, 256, 128};
        for (int ci = 0; ci < 10; ci++) {
            if ((size_t)cands[ci] * 7808 + 8192 <= arena_bytes) { RP = cands[ci]; break; }
        }
    }
    size_t ao = arenaO;
    auto aalloc = [&](size_t bytes) -> size_t { size_t r = ao; ao += (bytes + 255) & ~(size_t)255; return r; };
    const size_t AcbO = aalloc((size_t)RP*448*2);
    const size_t XcO  = aalloc((size_t)RP*384*4);
    const size_t LcO  = aalloc((size_t)RP*384*2);
    const size_t QTO  = aalloc((size_t)RP*384*2);
    const size_t T2O  = aalloc((size_t)RP*384*2);
    const size_t HhO  = aalloc((size_t)RP*1536*2);
    int TC = (int)(arena_bytes / 70200);
    TC &= ~7; if (TC > 2048) TC = 2048; if (TC < 8) TC = 8;
    size_t to = arenaO;
    auto talloc = [&](size_t bytes) -> size_t { size_t r = to; to += (bytes + 255) & ~(size_t)255; return r; };
    const size_t tk1O = talloc((size_t)TC*16*128*2);
    const size_t tk2O = talloc((size_t)TC*16*256*2);
    const size_t tgmO = talloc((size_t)TC*256*2);
    const size_t tcatO = talloc((size_t)TC*16*512*2);
    const size_t thbO = talloc((size_t)TC*16*512*2);
    const size_t t4oO = talloc((size_t)TC*16*384*4);

    auto F = [&](size_t off) -> float* { return (float*)(ws + off); };
    auto I = [&](size_t off) -> int* { return (int*)(ws + off); };
    auto U = [&](size_t off) -> unsigned char* { return (unsigned char*)(ws + off); };
    auto Bf = [&](size_t off) -> __bf16* { return (__bf16*)(ws + off); };
    auto ew = [](size_t n) -> dim3 { return dim3((unsigned)((n + 255) / 256)); };
    const int* flag = I(flagO);
    __bf16* WT = Bf(wtO);
    float* BF = F(bsO);
    const int b_t1 = 0, b_t2 = 128, b_t3 = 384, b_t4 = 896, b_u1 = 1280, b_u2 = 1664;

    auto gemm = [&](const __bf16* A, const __bf16* W, const float* bias, const float* res, void* C,
                    int M, int Ncol, int Kk, int relu, int obf) {
        dim3 g((unsigned)(Ncol / 128), (unsigned)(M / 128));
        gemm_kernel<<<g, 256, 0, stream>>>(A, W, bias, res, C, M, Ncol, Kk, relu, obf, nullptr);
    };
    auto gemm_pe = [&](const __bf16* A, const __bf16* W, const float* bias, void* C,
                       int M, int Ncol, int Kk, const float* pepos) {
        dim3 g((unsigned)(Ncol / 128), (unsigned)(M / 128));
        gemm_kernel<<<g, 256, 0, stream>>>(A, W, bias, nullptr, C, M, Ncol, Kk, 1, 0, pepos);
    };
    auto gemmln = [&](const float* A, const __bf16* W, const float* res, void* C,
                      int M, int Ncol, int relu, int obf) {
        dim3 g((unsigned)(Ncol / 128), (unsigned)(M / 128));
        gemmln_kernel<<<g, 256, 0, stream>>>(A, W, nullptr, res, C, M, Ncol, Dd, relu, obf);
    };
    auto ln2 = [&](const float* A, const float* B, __bf16* Y, int R) {
        ln2_kernel<<<dim3((R + 3) / 4), 256, 0, stream>>>(A, B, Y, R);
    };
    auto attn_old = [&](const float* Qp, const float* Kp, const float* Vp, const unsigned char* mask,
                        __bf16* Op, int Sq, int Sk, int nb, int xorv, int ldq, int ldkv) {
        attn_kernel<<<dim3(Sq, NHh, nb), 64, 0, stream>>>(Qp, Kp, Vp, mask, Op, Sq, Sk, xorv, ldq, ldkv);
    };
    auto attn_mfma = [&](const __bf16* Qp, const __bf16* Kp, const __bf16* Vp, __bf16* Op,
                         int ldq, int ldkv, int ldo, int rpb, int nb, int b0,
                         int bxor, const unsigned char* mask) {
        attn_mfma_kernel<<<dim3(rpb/128, NHh, nb), 256, 0, stream>>>(Qp, Kp, Vp, Op, ldq, ldkv, ldo, rpb, b0, bxor, mask);
    };
    __bf16* ctxb = Bf(cxO);

    auto ffn = [&](float* x, const __bf16* w1t, const __bf16* w2t, int R) {
        for (int r0 = 0; r0 < R; r0 += RP) {
            int rc = (R - r0 < RP) ? (R - r0) : RP;
            gemmln(x + (size_t)r0*Dd, w1t, nullptr, Bf(HhO), rc, FFf, 1, 1);
            gemm(Bf(HhO), w2t, nullptr, x + (size_t)r0*Dd, x + (size_t)r0*Dd, rc, Dd, FFf, 0, 0);
        }
    };
    // cross-encoder over 16 batches; ca pairs batch bq with bq^8
    auto cross_enc = [&](float* x, const unsigned char* mask, int S) {
        const int R = 16 * S;
        if (S == 128) {
            gemmln(x, WT + wt_cx, nullptr, Bf(qkvbO), R, 1152, 0, 1);
            attn_mfma(Bf(qkvbO), Bf(qkvbO) + 384, Bf(qkvbO) + 768, ctxb, 1152, 1152, Dd, 128, 16, 0, 0, mask);
            gemm(ctxb, WT + wt_cx + 3*DD, nullptr, x, x, R, Dd, Dd, 0, 0);
            gemmln(x, WT + wt_cx + 4*DD, nullptr, Bf(qkvbO), R, 1152, 0, 1);
            attn_mfma(Bf(qkvbO), Bf(qkvbO) + 384, Bf(qkvbO) + 768, ctxb, 1152, 1152, Dd, 128, 16, 0, 8, nullptr);
            gemm(ctxb, WT + wt_cx + 7*DD, nullptr, x, x, R, Dd, Dd, 0, 0);
        } else {
            gemmln(x, WT + wt_cx, nullptr, F(qkvbO), R, 1152, 0, 0);
            attn_old(F(qkvbO), F(qkvbO) + 384, F(qkvbO) + 768, mask, ctxb, S, S, 16, 0, 1152, 1152);
            gemm(ctxb, WT + wt_cx + 3*DD, nullptr, x, x, R, Dd, Dd, 0, 0);
            gemmln(x, WT + wt_cx + 4*DD, nullptr, F(qkvbO), R, 1152, 0, 0);
            attn_old(F(qkvbO), F(qkvbO) + 384, F(qkvbO) + 768, nullptr, ctxb, S, S, 16, 8, 1152, 1152);
            gemm(ctxb, WT + wt_cx + 7*DD, nullptr, x, x, R, Dd, Dd, 0, 0);
        }
        ffn(x, WT + wt_cf1, WT + wt_cf2, R);
    };
    // batched 4-layer decoder: x [16][Gc][Dd]; mem LN in lnm (bf16, 2048 rows)
    auto decoder4 = [&](float* x) {
        for (int l = 0; l < 4; l++) {
            gemmln(x, WT + wt_es + (size_t)l*4*DD, nullptr, Bf(qkvbO), 2048, 1152, 0, 1);
            attn_mfma(Bf(qkvbO), Bf(qkvbO) + 384, Bf(qkvbO) + 768, ctxb, 1152, 1152, Dd, 128, 16, 0, 0, nullptr);
            gemm(ctxb, WT + wt_es + (size_t)l*4*DD + 3*DD, nullptr, x, x, 2048, Dd, Dd, 0, 0);
            gemmln(x, WT + wt_ec + (size_t)l*4*DD, nullptr, Bf(qbO), 2048, Dd, 0, 1);
            gemm(Bf(lnmO), WT + wt_ec + (size_t)l*4*DD + DD, nullptr, nullptr, Bf(kvbO), 2048, 768, Dd, 0, 1);
            attn_mfma(Bf(qbO), Bf(kvbO), Bf(kvbO) + 384, ctxb, Dd, 768, Dd, 128, 16, 0, 0, nullptr);
            gemm(ctxb, WT + wt_ec + (size_t)l*4*DD + 3*DD, nullptr, x, x, 2048, Dd, Dd, 0, 0);
            ffn(x, WT + wt_ef1 + (size_t)l*DF, WT + wt_ef2 + (size_t)l*DF, 2048);
        }
    };

    // ---- pipeline ----
    detect_kernel<<<dim3(1), 256, 0, stream>>>((const unsigned int*)pos_src, I(flagO));
    cvtf_kernel<<<ew(PH), 256, 0, stream>>>(pos_src, F(posfO), PH, flag);
    cvtf_kernel<<<ew(PH), 256, 0, stream>>>(pos_tgt, F(posfO) + PH, PH, flag);
    cvtf_kernel<<<dim3(2), 256, 0, stream>>>(mtok, F(mtokO), (size_t)Dd, flag);

    auto wtr = [&](const void* src, size_t dstOff, int K, int N, int Kpad, int cnt) {
        wtr_kernel<<<ew((size_t)cnt * N * Kpad), 256, 0, stream>>>(src, WT + dstOff, K, N, Kpad, cnt, flag);
    };
    wtr(tw1, wt_t1, 3, 128, 64, 1);
    wtr(tw2, wt_t2, 128, 256, 128, 1);
    wtr(tw3, wt_t3, 512, 512, 512, 1);
    wtr(tw4, wt_t4, 512, 384, 512, 1);
    wtr(cxw, wt_cx, 384, 384, 384, 8);
    wtr(cff1, wt_cf1, 384, 1536, 384, 1);
    wtr(cff2, wt_cf2, 1536, 384, 1536, 1);
    wtr(esa, wt_es, 384, 384, 384, 16);
    wtr(eca, wt_ec, 384, 384, 384, 16);
    wtr(eff1, wt_ef1, 384, 1536, 384, 4);
    wtr(eff2, wt_ef2, 1536, 384, 1536, 4);
    wtr(dca, wt_dc, 384, 384, 384, 8);
    wtr(dff1, wt_df1, 384, 1536, 384, 2);
    wtr(dff2, wt_df2, 1536, 384, 1536, 2);
    wtr(uw1, wt_u1, 387, 384, 448, 1);
    wtr(uw2, wt_u2, 384, 384, 384, 1);
    cvtf_kernel<<<ew(128), 256, 0, stream>>>(tb1, BF + b_t1, 128, flag);
    cvtf_kernel<<<ew(256), 256, 0, stream>>>(tb2, BF + b_t2, 256, flag);
    cvtf_kernel<<<ew(512), 256, 0, stream>>>(tb3, BF + b_t3, 512, flag);
    cvtf_kernel<<<ew(384), 256, 0, stream>>>(tb4, BF + b_t4, 384, flag);
    cvtf_kernel<<<ew(384), 256, 0, stream>>>(ub1, BF + b_u1, 384, flag);
    cvtf_kernel<<<ew(384), 256, 0, stream>>>(ub2, BF + b_u2, 384, flag);

    fps_kernel<<<dim3(16), 256, 0, stream>>>(F(posfO), F(posfO) + PH, F(centO), F(centO) + (size_t)Bc*Gc*3);

    // tokenize both sides (16 batches)
    knn16_kernel<<<dim3(16*Gc), 64, 0, stream>>>(F(centO), F(posfO), I(nidxO), Gc, Nn);
    rel_kernel<<<ew((size_t)16*Gc*Kc*64), 256, 0, stream>>>(F(posfO), F(centO), I(nidxO), Bf(relbO), 16);
    for (int g0 = 0; g0 < 16*Gc; g0 += TC) {
        const int gc = (16*Gc - g0 < TC) ? (16*Gc - g0) : TC;
        const int RC = gc * Kc;
        gemm(Bf(relbO) + (size_t)g0*Kc*64, WT + wt_t1, BF + b_t1, nullptr, Bf(tk1O), RC, 128, 64, 1, 1);
        gemm(Bf(tk1O), WT + wt_t2, BF + b_t2, nullptr, Bf(tk2O), RC, 256, 128, 0, 1);
        maxk_bf_kernel<<<ew((size_t)gc*256), 256, 0, stream>>>(Bf(tk2O), Bf(tgmO), gc, 256);
        concat_gf_kernel<<<ew((size_t)RC*512), 256, 0, stream>>>(Bf(tgmO), Bf(tk2O), Bf(tcatO), gc);
        gemm(Bf(tcatO), WT + wt_t3, BF + b_t3, nullptr, Bf(thbO), RC, 512, 512, 1, 1);
        gemm(Bf(thbO), WT + wt_t4, BF + b_t4, nullptr, F(t4oO), RC, Dd, 512, 0, 0);
        maxk_f32_kernel<<<ew((size_t)gc*Dd), 256, 0, stream>>>(F(t4oO), F(tokO) + (size_t)g0*Dd, gc, Dd);
    }

    pe_kernel<<<ew((size_t)16*GD), 256, 0, stream>>>(F(cpeO), nullptr, F(centO), (size_t)16*GD);

    gather_rows_kernel<<<ew((size_t)Bc*Vc*Dd), 256, 0, stream>>>(F(tokO), vis_s, F(vtokO), Vc, Dd, Gc);
    gather_rows_kernel<<<ew((size_t)Bc*Vc*Dd), 256, 0, stream>>>(F(tokO) + 8*GD, vis_t, F(vtokO) + (size_t)8*Vc*Dd, Vc, Dd, Gc);
    gather_rows_kernel<<<ew((size_t)Bc*Vc*3), 256, 0, stream>>>(F(centO), vis_s, F(vis3O), Vc, 3, Gc);
    gather_rows_kernel<<<ew((size_t)Bc*Vc*3), 256, 0, stream>>>(F(centO) + (size_t)Bc*Gc*3, vis_t, F(vis3O) + (size_t)8*Vc*3, Vc, 3, Gc);

    zero_kernel<<<ew((size_t)16*Gc*Gc), 256, 0, stream>>>(U(mfullO), (size_t)16*Gc*Gc);
    knn16_kernel<<<dim3(16*Gc), 64, 0, stream>>>(F(centO), F(centO), I(nidxO), Gc, Gc);
    scatter_mask_kernel<<<ew((size_t)16*Gc*Kc), 256, 0, stream>>>(I(nidxO), U(mfullO), Gc, Gc, 16);
    zero_kernel<<<ew((size_t)16*Vc*Vc), 256, 0, stream>>>(U(mvisO), (size_t)16*Vc*Vc);
    knn16_kernel<<<dim3(16*Vc), 64, 0, stream>>>(F(vis3O), F(vis3O), I(nidxO), Vc, Vc);
    scatter_mask_kernel<<<ew((size_t)16*Vc*Kc), 256, 0, stream>>>(I(nidxO), U(mvisO), Vc, Vc, 16);

    cross_enc(F(vtokO), U(mvisO), Vc);
    cross_enc(F(tokO), U(mfullO), Gc);

    dec_init_kernel<<<ew((size_t)Bc*GD), 256, 0, stream>>>(F(mtokO), F(vtokO), F(cpeO), msk_s, vis_s, F(decxO));
    dec_init_kernel<<<ew((size_t)Bc*GD), 256, 0, stream>>>(F(mtokO), F(vtokO) + (size_t)8*Vc*Dd, F(cpeO) + 8*GD, msk_t, vis_t, F(decxO) + 8*GD);
    // decoder memory: src-decoder attends tgt tokens, tgt-decoder attends src tokens
    ln2(F(tokO) + 8*GD, F(cpeO) + 8*GD, Bf(lnmO), 1024);
    ln2(F(tokO), F(cpeO), Bf(lnmO) + (size_t)1024*Dd, 1024);
    decoder4(F(decxO));

    zero_kernel<<<dim3(1), 256, 0, stream>>>(U(accbO), 64);
    gather_rows_kernel<<<ew((size_t)Bc*Mc*Dd), 256, 0, stream>>>(F(tokO), msk_s, F(tbsO), Mc, Dd, Gc);
    gather_rows_kernel<<<ew((size_t)Bc*Mc*Dd), 256, 0, stream>>>(F(tokO) + 8*GD, msk_t, F(tbtO), Mc, Dd, Gc);
    sl1_kernel<<<ew((size_t)Bc*Mc*Dd), 256, 0, stream>>>(F(tbsO), F(decxO), F(accbO), 0);
    sl1_kernel<<<ew((size_t)Bc*Mc*Dd), 256, 0, stream>>>(F(tbtO), F(decxO) + 8*GD, F(accbO), 1);

    // ---- dense path, both sides fused ----
    knn3_kernel<<<dim3(16*Nn), 64, 0, stream>>>(F(posfO), F(centO), I(idx3O), F(w3O));
    ln2(F(tokO), F(cpeO), Bf(lnmO), 2048);
    gemm(Bf(lnmO), WT + wt_dc + 0*4*DD + DD, nullptr, nullptr, Bf(kvd0O), 2048, 768, Dd, 0, 1);
    gemm(Bf(lnmO), WT + wt_dc + 1*4*DD + DD, nullptr, nullptr, Bf(kvd1O), 2048, 768, Dd, 0, 1);
    const size_t kvdo[2] = {kvd0O, kvd1O};
    const int RT = 16 * Nn;
    for (int r0 = 0; r0 < RT; r0 += RP) {
        const int rpb = (RP < Nn) ? RP : Nn;
        const int nb = (RP < Nn) ? 1 : RP / Nn;
        const int b0 = r0 / Nn;
        interp_kernel<<<ew((size_t)RP*448), 256, 0, stream>>>(F(tokO), F(posfO), I(idx3O), F(w3O), Bf(AcbO), r0, RP);
        gemm(Bf(AcbO), WT + wt_u1, BF + b_u1, nullptr, Bf(LcO), RP, Dd, 448, 1, 1);
        gemm_pe(Bf(LcO), WT + wt_u2, BF + b_u2, F(XcO), RP, Dd, Dd, F(posfO) + (size_t)r0*3);
        for (int l = 0; l < 2; l++) {
            gemmln(F(XcO), WT + wt_dc + (size_t)l*4*DD, nullptr, Bf(QTO), RP, Dd, 0, 1);
            attn_mfma(Bf(QTO), Bf(kvdo[l]), Bf(kvdo[l]) + 384, Bf(T2O), Dd, 768, Dd, rpb, nb, b0, 0, nullptr);
            gemm(Bf(T2O), WT + wt_dc + (size_t)l*4*DD + 3*DD, nullptr, F(XcO), F(XcO), RP, Dd, Dd, 0, 0);
            gemmln(F(XcO), WT + wt_df1 + (size_t)l*DF, nullptr, Bf(HhO), RP, FFf, 1, 1);
            if (l == 1)
                gemm(Bf(HhO), WT + wt_df2 + DF, nullptr, F(XcO), out + (size_t)r0*Dd, RP, Dd, FFf, 0, 0);
            else
                gemm(Bf(HhO), WT + wt_df2, nullptr, F(XcO), F(XcO), RP, Dd, FFf, 0, 0);
        }
    }

    mae_finalize_kernel<<<dim3(1), 1, 0, stream>>>(F(accbO), out + (size_t)2*Bc*Nn*Dd);
}